// Round 6
// baseline (484.425 us; speedup 1.0000x reference)
//
#include <hip/hip_runtime.h>
#include <hip/hip_bf16.h>
#include <math.h>

#define TT 512
#define NN 200
#define HH 64
#define EE 16
#define RR 10
#define MU_OFF 0
#define COV_OFF (TT*NN)      // 102400
#define HBLK (NN*NN)         // 40000 floats per t-block of cov
#define HPAD 68              // padded hist row

__device__ __forceinline__ float sigmoidf_(float x) {
    return 1.0f / (1.0f + __expf(-x));
}
__device__ __forceinline__ float tanhf_(float x) {
    x = fminf(15.0f, fmaxf(-15.0f, x));
    float e = __expf(2.0f * x);
    return (e - 1.0f) / (e + 1.0f);
}

// Raw wave-counted barrier: waits LDS only (lgkmcnt), never drains vmcnt,
// so the periodic global flush stores float across ticks.
#define BAR() do { asm volatile("s_waitcnt lgkmcnt(0)" ::: "memory"); \
                   __builtin_amdgcn_s_barrier();                      \
                   asm volatile("" ::: "memory"); } while (0)

// Make a loaded float4 opaque: the backend can no longer rematerialize the
// load inside the t-loop (R2/R4/R5 all sank the weight loads into the loop,
// re-pulling 128 KB/WG/tick from L2 -> the 444us plateau). Costs nothing.
#define PIN4(v) asm volatile("" : "+v"(v.x), "+v"(v.y), "+v"(v.z), "+v"(v.w))

// Apply macro M for q = 0..15
#define RQ(M) M(0) M(1) M(2) M(3) M(4) M(5) M(6) M(7) \
              M(8) M(9) M(10) M(11) M(12) M(13) M(14) M(15)

// ---------------- Kernel A: 2-layer LSTM, layer-pipelined, 1 WG per batch ---
// Waves 0-3: layer0 gate rows (step t).  Waves 4-7: layer1 gate rows (step t-1).
__global__
__attribute__((amdgpu_flat_work_group_size(512, 512), amdgpu_waves_per_eu(2, 2)))
void lstm_kernel(
    const float* __restrict__ inputs,
    const float* __restrict__ Wih0, const float* __restrict__ Whh0,
    const float* __restrict__ bih0, const float* __restrict__ bhh0,
    const float* __restrict__ Wih1, const float* __restrict__ Whh1,
    const float* __restrict__ bih1, const float* __restrict__ bhh1,
    float* __restrict__ out)
{
    const int n = blockIdx.x;
    const int tid = threadIdx.x;

    __shared__ float xs[TT];
    __shared__ float h0s[HH];
    __shared__ float h1s[HH];
    __shared__ float ga0[256];          // activated layer0 gates
    __shared__ float ga1[256];          // activated layer1 gates
    __shared__ float hist[64][HPAD];    // h1 history, flushed every 64 ticks

    xs[tid] = inputs[tid * NN + n];
    if (tid < HH) { h0s[tid] = 0.0f; h1s[tid] = 0.0f; }

    float* covbase = out + COV_OFF + n * HH;

    if (tid < 256) {
        // ================= layer-0 branch (waves 0-3) =================
        const float4* p0 = (const float4*)(Whh0 + tid * HH);
#define DECLA(q) float4 wA##q = p0[q]; PIN4(wA##q);
        RQ(DECLA)
        const float wx = Wih0[tid];
        const float b0 = bih0[tid] + bhh0[tid];
        const bool  upd = (tid < HH);          // wave 0 updates c0/h0
        const int   gate = tid >> 6;           // wave-uniform
        float c0 = 0.0f;

        BAR();  // init barrier

        for (int t = 0; t <= TT; ++t) {
            if (t < TT) {
                float a0 = fmaf(wx, xs[t], b0), a1 = 0.f, a2 = 0.f, a3 = 0.f;
                const float4* h4 = (const float4*)h0s;
#define FMAA(q) { float4 h = h4[q];                  \
                  a0 = fmaf(wA##q.x, h.x, a0);       \
                  a1 = fmaf(wA##q.y, h.y, a1);       \
                  a2 = fmaf(wA##q.z, h.z, a2);       \
                  a3 = fmaf(wA##q.w, h.w, a3); }
                RQ(FMAA)
                float g = (a0 + a1) + (a2 + a3);
                ga0[tid] = (gate == 2) ? tanhf_(g) : sigmoidf_(g);
            }
            BAR();
            if (t < TT && upd) {
                float ia = ga0[tid], fa = ga0[tid + 64];
                float gg = ga0[tid + 128], oa = ga0[tid + 192];
                c0 = fmaf(fa, c0, ia * gg);
                h0s[tid] = oa * tanhf_(c0);
            }
            BAR();
            if ((t & 63) == 0 && t > 0) {   // flush steps t-64..t-1
                const int s = tid >> 3;
                const int c = (tid & 7) * 8;
                float4 v0 = *(const float4*)&hist[s][c];
                float4 v1 = *(const float4*)&hist[s][c + 4];
                float* dst = covbase + (size_t)(t - 64 + s) * HBLK + c;
                ((float4*)dst)[0] = v0;
                ((float4*)dst)[1] = v1;
            }
        }
    } else {
        // ================= layer-1 branch (waves 4-7) =================
        const int r = tid - 256;
        const float4* pi = (const float4*)(Wih1 + r * HH);
        const float4* ph = (const float4*)(Whh1 + r * HH);
#define DECLB(q) float4 wI##q = pi[q]; PIN4(wI##q); \
                 float4 wH##q = ph[q]; PIN4(wH##q);
        RQ(DECLB)
        const float b1 = bih1[r] + bhh1[r];
        const bool  upd = (r < HH);            // wave 4 updates c1/h1
        const int   gate = r >> 6;             // wave-uniform
        float c1 = 0.0f;

        BAR();  // init barrier

        for (int t = 0; t <= TT; ++t) {
            if (t >= 1) {
                // layer1 for step t-1: inputs h0[t-1] (current h0s), h1[t-2] (current h1s)
                float a0 = b1, a1 = 0.f, a2 = 0.f, a3 = 0.f;
                float s0 = 0.f, s1 = 0.f, s2 = 0.f, s3 = 0.f;
                const float4* ha = (const float4*)h0s;
                const float4* hb = (const float4*)h1s;
#define FMAB(q) { float4 x = ha[q]; float4 y = hb[q]; \
                  a0 = fmaf(wI##q.x, x.x, a0);        \
                  a1 = fmaf(wI##q.y, x.y, a1);        \
                  a2 = fmaf(wI##q.z, x.z, a2);        \
                  a3 = fmaf(wI##q.w, x.w, a3);        \
                  s0 = fmaf(wH##q.x, y.x, s0);        \
                  s1 = fmaf(wH##q.y, y.y, s1);        \
                  s2 = fmaf(wH##q.z, y.z, s2);        \
                  s3 = fmaf(wH##q.w, y.w, s3); }
                RQ(FMAB)
                float g = ((a0 + a1) + (a2 + a3)) + ((s0 + s1) + (s2 + s3));
                ga1[r] = (gate == 2) ? tanhf_(g) : sigmoidf_(g);
            }
            BAR();
            if (t >= 1 && upd) {
                float ia = ga1[r], fa = ga1[r + 64];
                float gg = ga1[r + 128], oa = ga1[r + 192];
                c1 = fmaf(fa, c1, ia * gg);
                float h1 = oa * tanhf_(c1);
                h1s[r] = h1;
                hist[(t - 1) & 63][r] = h1;
            }
            BAR();
            if ((t & 63) == 0 && t > 0) {   // flush steps t-64..t-1
                const int s = tid >> 3;
                const int c = (tid & 7) * 8;
                float4 v0 = *(const float4*)&hist[s][c];
                float4 v1 = *(const float4*)&hist[s][c + 4];
                float* dst = covbase + (size_t)(t - 64 + s) * HBLK + c;
                ((float4*)dst)[0] = v0;
                ((float4*)dst)[1] = v1;
            }
        }
    }
}

// ---------------- Kernel B: heads + covariance, one workgroup per t ----------
__global__ __launch_bounds__(256) void head_kernel(
    const float* __restrict__ embW, const int* __restrict__ indices,
    const float* __restrict__ Wm, const float* __restrict__ bm,
    const float* __restrict__ Wv, const float* __restrict__ bv,
    const float* __restrict__ Wd, const float* __restrict__ bd,
    float* __restrict__ out)
{
    const int t = blockIdx.x;
    const int tid = threadIdx.x;

    __shared__ float hs[NN * HH];          // 12800
    __shared__ float embs[NN * EE];        // 3200
    __shared__ float Wvs[(HH + EE) * RR];  // 800
    __shared__ float Wms[HH + EE];
    __shared__ float Wds[HH + EE];
    __shared__ float Vs[NN * (RR + 1)];    // stride 11 to dodge bank conflicts
    __shared__ float dsh[NN];
    __shared__ float bvs[RR];

    const float* hsrc = out + COV_OFF + (size_t)t * HBLK;
    for (int i = tid; i < (NN * HH) / 4; i += 256)
        ((float4*)hs)[i] = ((const float4*)hsrc)[i];
    for (int i = tid; i < NN * EE; i += 256) {
        int n = i >> 4, e = i & 15;
        embs[i] = embW[indices[n] * EE + e];
    }
    for (int i = tid; i < (HH + EE) * RR; i += 256) Wvs[i] = Wv[i];
    if (tid < HH + EE) { Wms[tid] = Wm[tid]; Wds[tid] = Wd[tid]; }
    if (tid < RR) bvs[tid] = bv[tid];
    __syncthreads();

    // V = y @ Wv + bv
    for (int p = tid; p < NN * RR; p += 256) {
        int n = p / RR, r = p - n * RR;
        const float* hn = hs + n * HH;
        const float* en = embs + n * EE;
        float acc = bvs[r];
#pragma unroll 8
        for (int k = 0; k < HH; ++k) acc = fmaf(hn[k], Wvs[k * RR + r], acc);
#pragma unroll
        for (int k = 0; k < EE; ++k) acc = fmaf(en[k], Wvs[(HH + k) * RR + r], acc);
        Vs[n * (RR + 1) + r] = acc;
    }
    // mu and d
    const float bmv = bm[0], bdv = bd[0];
    for (int n = tid; n < NN; n += 256) {
        const float* hn = hs + n * HH;
        const float* en = embs + n * EE;
        float am = bmv, ad = bdv;
#pragma unroll 8
        for (int k = 0; k < HH; ++k) {
            float h = hn[k];
            am = fmaf(h, Wms[k], am);
            ad = fmaf(h, Wds[k], ad);
        }
#pragma unroll
        for (int k = 0; k < EE; ++k) {
            float e = en[k];
            am = fmaf(e, Wms[HH + k], am);
            ad = fmaf(e, Wds[HH + k], ad);
        }
        out[MU_OFF + t * NN + n] = am;
        dsh[n] = (ad > 20.0f) ? ad : log1pf(__expf(ad));  // softplus
    }
    __syncthreads();

    // cov[t] = V V^T + diag(d)  — overwrites the whole block (incl. stashed h)
    float* covp = out + COV_OFF + (size_t)t * HBLK;
    for (int p = tid; p < NN * NN; p += 256) {
        int n = p / NN, m = p - n * NN;
        const float* vn = Vs + n * (RR + 1);
        const float* vm = Vs + m * (RR + 1);
        float acc = (n == m) ? dsh[n] : 0.0f;
#pragma unroll
        for (int r = 0; r < RR; ++r) acc = fmaf(vn[r], vm[r], acc);
        covp[p] = acc;
    }
}

extern "C" void kernel_launch(void* const* d_in, const int* in_sizes, int n_in,
                              void* d_out, int out_size, void* d_ws, size_t ws_size,
                              hipStream_t stream) {
    const float* inputs  = (const float*)d_in[0];
    const int*   indices = (const int*)d_in[1];
    const float* embW    = (const float*)d_in[2];
    const float* Wih0    = (const float*)d_in[3];
    const float* Whh0    = (const float*)d_in[4];
    const float* bih0    = (const float*)d_in[5];
    const float* bhh0    = (const float*)d_in[6];
    const float* Wih1    = (const float*)d_in[7];
    const float* Whh1    = (const float*)d_in[8];
    const float* bih1    = (const float*)d_in[9];
    const float* bhh1    = (const float*)d_in[10];
    const float* Wm      = (const float*)d_in[11];
    const float* bm      = (const float*)d_in[12];
    const float* Wv      = (const float*)d_in[13];
    const float* bv      = (const float*)d_in[14];
    const float* Wd      = (const float*)d_in[15];
    const float* bd      = (const float*)d_in[16];
    float* out = (float*)d_out;

    lstm_kernel<<<NN, 512, 0, stream>>>(inputs, Wih0, Whh0, bih0, bhh0,
                                        Wih1, Whh1, bih1, bhh1, out);
    head_kernel<<<TT, 256, 0, stream>>>(embW, indices, Wm, bm, Wv, bv, Wd, bd, out);
}

// Round 7
// 387.324 us; speedup vs baseline: 1.2507x; 1.2507x over previous
//
#include <hip/hip_runtime.h>
#include <hip/hip_bf16.h>
#include <math.h>

#define TT 512
#define NN 200
#define HH 64
#define EE 16
#define RR 10
#define MU_OFF 0
#define COV_OFF (TT*NN)      // 102400
#define HBLK (NN*NN)         // 40000 floats per t-block of cov
#define HPAD 68              // padded hist row

__device__ __forceinline__ float sigmoidf_(float x) {
    return 1.0f / (1.0f + __expf(-x));
}
__device__ __forceinline__ float tanhf_(float x) {
    x = fminf(15.0f, fmaxf(-15.0f, x));
    float e = __expf(2.0f * x);
    return (e - 1.0f) / (e + 1.0f);
}
// unified gate activation: sigmoid(g) or tanh(g)=2*sigmoid(2g)-1 (one exp+rcp)
__device__ __forceinline__ float act_(float g, bool is_tanh) {
    float xx = is_tanh ? 2.0f * g : g;
    float e = __expf(-xx);
    float v = 1.0f / (1.0f + e);
    return is_tanh ? fmaf(2.0f, v, -1.0f) : v;
}

// quad_perm DPP xor-swaps (VALU pipe, NOT LDS pipe — that's the point)
__device__ __forceinline__ float dppxor1(float v) {   // lanes [1,0,3,2]
    return __int_as_float(__builtin_amdgcn_mov_dpp(__float_as_int(v), 0xB1, 0xf, 0xf, true));
}
__device__ __forceinline__ float dppxor2(float v) {   // lanes [2,3,0,1]
    return __int_as_float(__builtin_amdgcn_mov_dpp(__float_as_int(v), 0x4E, 0xf, 0xf, true));
}

// Raw wave-counted barrier: waits LDS only (lgkmcnt), never drains vmcnt.
#define BAR() do { asm volatile("s_waitcnt lgkmcnt(0)" ::: "memory"); \
                   __builtin_amdgcn_s_barrier();                      \
                   asm volatile("" ::: "memory"); } while (0)

#define PIN4(v) asm volatile("" : "+v"(v.x), "+v"(v.y), "+v"(v.z), "+v"(v.w))
#define RM4(M) M(0) M(1) M(2) M(3)

// ---------------- Kernel A: 2-layer LSTM, layer-pipelined, 1 WG per batch ---
// Waves 0-3: layer0 (step t). Waves 4-7: layer1 (step t-1).
// Quad-split matvec: thread handles 4 rows x 16-k-quarter; h read = 4 (A) or
// 8 (B) ds_read_b128 per thread instead of 16/32 wave-uniform broadcasts.
// (R1-R6 were LDS-return-bandwidth-bound: 192 b128/CU/tick ~ 2070cy = dur.)
__global__
__attribute__((amdgpu_flat_work_group_size(512, 512), amdgpu_waves_per_eu(2, 2)))
void lstm_kernel(
    const float* __restrict__ inputs,
    const float* __restrict__ Wih0, const float* __restrict__ Whh0,
    const float* __restrict__ bih0, const float* __restrict__ bhh0,
    const float* __restrict__ Wih1, const float* __restrict__ Whh1,
    const float* __restrict__ bih1, const float* __restrict__ bhh1,
    float* __restrict__ out)
{
    const int n = blockIdx.x;
    const int tid = threadIdx.x;

    __shared__ float xs[TT];
    __shared__ float h0s[HH];
    __shared__ float h1s[HH];
    __shared__ float ga0[256];          // activated layer0 gates
    __shared__ float ga1[256];          // activated layer1 gates
    __shared__ float hist[64][HPAD];    // h1 history, flushed every 64 ticks

    xs[tid] = inputs[tid * NN + n];
    if (tid < HH) { h0s[tid] = 0.0f; h1s[tid] = 0.0f; }

    float* covbase = out + COV_OFF + n * HH;

    if (tid < 256) {
        // ================= layer-0 branch (waves 0-3) =================
        const int b4 = tid & ~3;        // first of this thread's 4 rows
        const int qr = tid & 3;         // k-quarter (16 floats)
#define DECLA(m) \
        float4 wA##m##_0, wA##m##_1, wA##m##_2, wA##m##_3; \
        { const float4* p = (const float4*)(Whh0 + (b4 + m) * HH + qr * 16); \
          wA##m##_0 = p[0]; wA##m##_1 = p[1]; wA##m##_2 = p[2]; wA##m##_3 = p[3]; \
          PIN4(wA##m##_0); PIN4(wA##m##_1); PIN4(wA##m##_2); PIN4(wA##m##_3); }
        RM4(DECLA)
#define DECLAB(m) const float wx##m = Wih0[b4 + m]; \
                  const float bb##m = bih0[b4 + m] + bhh0[b4 + m];
        RM4(DECLAB)
        const bool is_t = ((tid >> 6) == 2);   // gate 2 rows use tanh (wave-uniform)
        const bool upd = (tid < HH);
        float c0 = 0.0f;

        BAR();  // init barrier

        for (int t = 0; t <= TT; ++t) {
            if (t < TT) {
                const float x = xs[t];
                const float4* hq = (const float4*)(h0s + qr * 16);
                float4 hc0 = hq[0], hc1 = hq[1], hc2 = hq[2], hc3 = hq[3];
                float acc0, acc1, acc2, acc3;
#define MVA(m) { \
                float a = (qr == 0) ? fmaf(wx##m, x, bb##m) : 0.0f; \
                a = fmaf(wA##m##_0.x, hc0.x, a); \
                a = fmaf(wA##m##_0.y, hc0.y, a); \
                a = fmaf(wA##m##_0.z, hc0.z, a); \
                a = fmaf(wA##m##_0.w, hc0.w, a); \
                a = fmaf(wA##m##_1.x, hc1.x, a); \
                a = fmaf(wA##m##_1.y, hc1.y, a); \
                a = fmaf(wA##m##_1.z, hc1.z, a); \
                a = fmaf(wA##m##_1.w, hc1.w, a); \
                a = fmaf(wA##m##_2.x, hc2.x, a); \
                a = fmaf(wA##m##_2.y, hc2.y, a); \
                a = fmaf(wA##m##_2.z, hc2.z, a); \
                a = fmaf(wA##m##_2.w, hc2.w, a); \
                a = fmaf(wA##m##_3.x, hc3.x, a); \
                a = fmaf(wA##m##_3.y, hc3.y, a); \
                a = fmaf(wA##m##_3.z, hc3.z, a); \
                a = fmaf(wA##m##_3.w, hc3.w, a); \
                acc##m = a; }
                RM4(MVA)
                acc0 += dppxor1(acc0); acc0 += dppxor2(acc0);
                acc1 += dppxor1(acc1); acc1 += dppxor2(acc1);
                acc2 += dppxor1(acc2); acc2 += dppxor2(acc2);
                acc3 += dppxor1(acc3); acc3 += dppxor2(acc3);
                float g = (qr == 0) ? acc0 : (qr == 1) ? acc1 : (qr == 2) ? acc2 : acc3;
                ga0[tid] = act_(g, is_t);   // row == tid
            }
            BAR();
            if (t < TT && upd) {
                float ia = ga0[tid], fa = ga0[tid + 64];
                float gg = ga0[tid + 128], oa = ga0[tid + 192];
                c0 = fmaf(fa, c0, ia * gg);
                h0s[tid] = oa * tanhf_(c0);
            }
            BAR();
            if ((t & 63) == 0 && t > 0) {   // flush steps t-64..t-1 (A half)
                const int s = tid >> 3;
                const int c = (tid & 7) * 8;
                float4 v0 = *(const float4*)&hist[s][c];
                float4 v1 = *(const float4*)&hist[s][c + 4];
                float* dst = covbase + (size_t)(t - 64 + s) * HBLK + c;
                ((float4*)dst)[0] = v0;
                ((float4*)dst)[1] = v1;
            }
        }
    } else {
        // ================= layer-1 branch (waves 4-7) =================
        const int r = tid - 256;
        const int b4 = r & ~3;
        const int qr = r & 3;
#define DECLB(m) \
        float4 wI##m##_0, wI##m##_1, wI##m##_2, wI##m##_3; \
        float4 wH##m##_0, wH##m##_1, wH##m##_2, wH##m##_3; \
        { const float4* p = (const float4*)(Wih1 + (b4 + m) * HH + qr * 16); \
          wI##m##_0 = p[0]; wI##m##_1 = p[1]; wI##m##_2 = p[2]; wI##m##_3 = p[3]; \
          PIN4(wI##m##_0); PIN4(wI##m##_1); PIN4(wI##m##_2); PIN4(wI##m##_3); \
          const float4* q2 = (const float4*)(Whh1 + (b4 + m) * HH + qr * 16); \
          wH##m##_0 = q2[0]; wH##m##_1 = q2[1]; wH##m##_2 = q2[2]; wH##m##_3 = q2[3]; \
          PIN4(wH##m##_0); PIN4(wH##m##_1); PIN4(wH##m##_2); PIN4(wH##m##_3); }
        RM4(DECLB)
#define DECLBB(m) const float bB##m = bih1[b4 + m] + bhh1[b4 + m];
        RM4(DECLBB)
        const bool is_t = ((r >> 6) == 2);
        const bool upd = (r < HH);
        float c1 = 0.0f;

        BAR();  // init barrier

        for (int t = 0; t <= TT; ++t) {
            if (t >= 1) {
                const float4* hq = (const float4*)(h0s + qr * 16);
                const float4* gq = (const float4*)(h1s + qr * 16);
                float4 xc0 = hq[0], xc1 = hq[1], xc2 = hq[2], xc3 = hq[3];
                float4 yc0 = gq[0], yc1 = gq[1], yc2 = gq[2], yc3 = gq[3];
                float acc0, acc1, acc2, acc3;
#define MVB(m) { \
                float a = (qr == 0) ? bB##m : 0.0f; \
                float s2 = 0.0f; \
                a  = fmaf(wI##m##_0.x, xc0.x, a); \
                a  = fmaf(wI##m##_0.y, xc0.y, a); \
                a  = fmaf(wI##m##_0.z, xc0.z, a); \
                a  = fmaf(wI##m##_0.w, xc0.w, a); \
                a  = fmaf(wI##m##_1.x, xc1.x, a); \
                a  = fmaf(wI##m##_1.y, xc1.y, a); \
                a  = fmaf(wI##m##_1.z, xc1.z, a); \
                a  = fmaf(wI##m##_1.w, xc1.w, a); \
                a  = fmaf(wI##m##_2.x, xc2.x, a); \
                a  = fmaf(wI##m##_2.y, xc2.y, a); \
                a  = fmaf(wI##m##_2.z, xc2.z, a); \
                a  = fmaf(wI##m##_2.w, xc2.w, a); \
                a  = fmaf(wI##m##_3.x, xc3.x, a); \
                a  = fmaf(wI##m##_3.y, xc3.y, a); \
                a  = fmaf(wI##m##_3.z, xc3.z, a); \
                a  = fmaf(wI##m##_3.w, xc3.w, a); \
                s2 = fmaf(wH##m##_0.x, yc0.x, s2); \
                s2 = fmaf(wH##m##_0.y, yc0.y, s2); \
                s2 = fmaf(wH##m##_0.z, yc0.z, s2); \
                s2 = fmaf(wH##m##_0.w, yc0.w, s2); \
                s2 = fmaf(wH##m##_1.x, yc1.x, s2); \
                s2 = fmaf(wH##m##_1.y, yc1.y, s2); \
                s2 = fmaf(wH##m##_1.z, yc1.z, s2); \
                s2 = fmaf(wH##m##_1.w, yc1.w, s2); \
                s2 = fmaf(wH##m##_2.x, yc2.x, s2); \
                s2 = fmaf(wH##m##_2.y, yc2.y, s2); \
                s2 = fmaf(wH##m##_2.z, yc2.z, s2); \
                s2 = fmaf(wH##m##_2.w, yc2.w, s2); \
                s2 = fmaf(wH##m##_3.x, yc3.x, s2); \
                s2 = fmaf(wH##m##_3.y, yc3.y, s2); \
                s2 = fmaf(wH##m##_3.z, yc3.z, s2); \
                s2 = fmaf(wH##m##_3.w, yc3.w, s2); \
                acc##m = a + s2; }
                RM4(MVB)
                acc0 += dppxor1(acc0); acc0 += dppxor2(acc0);
                acc1 += dppxor1(acc1); acc1 += dppxor2(acc1);
                acc2 += dppxor1(acc2); acc2 += dppxor2(acc2);
                acc3 += dppxor1(acc3); acc3 += dppxor2(acc3);
                float g = (qr == 0) ? acc0 : (qr == 1) ? acc1 : (qr == 2) ? acc2 : acc3;
                ga1[r] = act_(g, is_t);     // row == r
            }
            BAR();
            if (t >= 1 && upd) {
                float ia = ga1[r], fa = ga1[r + 64];
                float gg = ga1[r + 128], oa = ga1[r + 192];
                c1 = fmaf(fa, c1, ia * gg);
                float h1 = oa * tanhf_(c1);
                h1s[r] = h1;
                hist[(t - 1) & 63][r] = h1;
            }
            BAR();
            if ((t & 63) == 0 && t > 0) {   // flush steps t-64..t-1 (B half)
                const int s = tid >> 3;
                const int c = (tid & 7) * 8;
                float4 v0 = *(const float4*)&hist[s][c];
                float4 v1 = *(const float4*)&hist[s][c + 4];
                float* dst = covbase + (size_t)(t - 64 + s) * HBLK + c;
                ((float4*)dst)[0] = v0;
                ((float4*)dst)[1] = v1;
            }
        }
    }
}

// ---------------- Kernel B: heads + covariance, one workgroup per t ----------
__global__ __launch_bounds__(256) void head_kernel(
    const float* __restrict__ embW, const int* __restrict__ indices,
    const float* __restrict__ Wm, const float* __restrict__ bm,
    const float* __restrict__ Wv, const float* __restrict__ bv,
    const float* __restrict__ Wd, const float* __restrict__ bd,
    float* __restrict__ out)
{
    const int t = blockIdx.x;
    const int tid = threadIdx.x;

    __shared__ float hs[NN * HH];          // 12800
    __shared__ float embs[NN * EE];        // 3200
    __shared__ float Wvs[(HH + EE) * RR];  // 800
    __shared__ float Wms[HH + EE];
    __shared__ float Wds[HH + EE];
    __shared__ float Vs[NN * (RR + 1)];    // stride 11 to dodge bank conflicts
    __shared__ float dsh[NN];
    __shared__ float bvs[RR];

    const float* hsrc = out + COV_OFF + (size_t)t * HBLK;
    for (int i = tid; i < (NN * HH) / 4; i += 256)
        ((float4*)hs)[i] = ((const float4*)hsrc)[i];
    for (int i = tid; i < NN * EE; i += 256) {
        int n = i >> 4, e = i & 15;
        embs[i] = embW[indices[n] * EE + e];
    }
    for (int i = tid; i < (HH + EE) * RR; i += 256) Wvs[i] = Wv[i];
    if (tid < HH + EE) { Wms[tid] = Wm[tid]; Wds[tid] = Wd[tid]; }
    if (tid < RR) bvs[tid] = bv[tid];
    __syncthreads();

    // V = y @ Wv + bv
    for (int p = tid; p < NN * RR; p += 256) {
        int n = p / RR, r = p - n * RR;
        const float* hn = hs + n * HH;
        const float* en = embs + n * EE;
        float acc = bvs[r];
#pragma unroll 8
        for (int k = 0; k < HH; ++k) acc = fmaf(hn[k], Wvs[k * RR + r], acc);
#pragma unroll
        for (int k = 0; k < EE; ++k) acc = fmaf(en[k], Wvs[(HH + k) * RR + r], acc);
        Vs[n * (RR + 1) + r] = acc;
    }
    // mu and d
    const float bmv = bm[0], bdv = bd[0];
    for (int n = tid; n < NN; n += 256) {
        const float* hn = hs + n * HH;
        const float* en = embs + n * EE;
        float am = bmv, ad = bdv;
#pragma unroll 8
        for (int k = 0; k < HH; ++k) {
            float h = hn[k];
            am = fmaf(h, Wms[k], am);
            ad = fmaf(h, Wds[k], ad);
        }
#pragma unroll
        for (int k = 0; k < EE; ++k) {
            float e = en[k];
            am = fmaf(e, Wms[HH + k], am);
            ad = fmaf(e, Wds[HH + k], ad);
        }
        out[MU_OFF + t * NN + n] = am;
        dsh[n] = (ad > 20.0f) ? ad : log1pf(__expf(ad));  // softplus
    }
    __syncthreads();

    // cov[t] = V V^T + diag(d)  — overwrites the whole block (incl. stashed h)
    float* covp = out + COV_OFF + (size_t)t * HBLK;
    for (int p = tid; p < NN * NN; p += 256) {
        int n = p / NN, m = p - n * NN;
        const float* vn = Vs + n * (RR + 1);
        const float* vm = Vs + m * (RR + 1);
        float acc = (n == m) ? dsh[n] : 0.0f;
#pragma unroll
        for (int r = 0; r < RR; ++r) acc = fmaf(vn[r], vm[r], acc);
        covp[p] = acc;
    }
}

extern "C" void kernel_launch(void* const* d_in, const int* in_sizes, int n_in,
                              void* d_out, int out_size, void* d_ws, size_t ws_size,
                              hipStream_t stream) {
    const float* inputs  = (const float*)d_in[0];
    const int*   indices = (const int*)d_in[1];
    const float* embW    = (const float*)d_in[2];
    const float* Wih0    = (const float*)d_in[3];
    const float* Whh0    = (const float*)d_in[4];
    const float* bih0    = (const float*)d_in[5];
    const float* bhh0    = (const float*)d_in[6];
    const float* Wih1    = (const float*)d_in[7];
    const float* Whh1    = (const float*)d_in[8];
    const float* bih1    = (const float*)d_in[9];
    const float* bhh1    = (const float*)d_in[10];
    const float* Wm      = (const float*)d_in[11];
    const float* bm      = (const float*)d_in[12];
    const float* Wv      = (const float*)d_in[13];
    const float* bv      = (const float*)d_in[14];
    const float* Wd      = (const float*)d_in[15];
    const float* bd      = (const float*)d_in[16];
    float* out = (float*)d_out;

    lstm_kernel<<<NN, 512, 0, stream>>>(inputs, Wih0, Whh0, bih0, bhh0,
                                        Wih1, Whh1, bih1, bhh1, out);
    head_kernel<<<TT, 256, 0, stream>>>(embW, indices, Wm, bm, Wv, bv, Wd, bd, out);
}